// Round 1
// baseline (691.681 us; speedup 1.0000x reference)
//
#include <hip/hip_runtime.h>
#include <stdint.h>

typedef unsigned short u16;
typedef __bf16 bf16x8 __attribute__((ext_vector_type(8)));
typedef float f32x4 __attribute__((ext_vector_type(4)));

#define NB 4
#define NC 512
#define NG 32
#define NSEQ 4096
#define NM (NB*NSEQ)

__device__ __forceinline__ u16 f2bf(float f){
  uint32_t u = __builtin_bit_cast(uint32_t, f);
  u += 0x7FFFu + ((u >> 16) & 1u);
  return (u16)(u >> 16);
}

__global__ void k_zero(float* p, int n){
  int i = blockIdx.x*blockDim.x + threadIdx.x;
  if (i < n) p[i] = 0.f;
}

// GroupNorm partial sums: grid = NB*NG*8 chunks, block 256
__global__ __launch_bounds__(256) void k_gn_stats(const float* __restrict__ x, float* __restrict__ stats){
  int blk = blockIdx.x;
  int ch = blk & 7, bg = blk >> 3;
  int g = bg & (NG-1), b = bg >> 5;
  int t = threadIdx.x;
  const float* base = x + (size_t)b*NSEQ*NC + g*16 + (t&3)*4;
  float s1 = 0.f, s2 = 0.f;
  for (int p = ch*512 + (t>>2); p < (ch+1)*512; p += 64){
    float4 v = *(const float4*)(base + (size_t)p*NC);
    s1 += v.x+v.y+v.z+v.w;
    s2 += v.x*v.x + v.y*v.y + v.z*v.z + v.w*v.w;
  }
  #pragma unroll
  for (int o = 32; o; o >>= 1){ s1 += __shfl_xor(s1, o); s2 += __shfl_xor(s2, o); }
  __shared__ float a1[4], a2[4];
  if ((t & 63) == 0){ a1[t>>6] = s1; a2[t>>6] = s2; }
  __syncthreads();
  if (t == 0){
    atomicAdd(&stats[bg*2+0], a1[0]+a1[1]+a1[2]+a1[3]);
    atomicAdd(&stats[bg*2+1], a2[0]+a2[1]+a2[2]+a2[3]);
  }
}

// normalize + affine, write bf16 hn [NM][NC]
__global__ __launch_bounds__(256) void k_gn_apply(const float* __restrict__ x, const float* __restrict__ stats,
    const float* __restrict__ gsc, const float* __restrict__ gbi, u16* __restrict__ hn){
  const float inv_cnt = 1.f/((float)NSEQ*16.f);
  size_t total = (size_t)NM*NC/4;
  for (size_t i = (size_t)blockIdx.x*blockDim.x + threadIdx.x; i < total; i += (size_t)gridDim.x*blockDim.x){
    size_t flat = i*4;
    int c = (int)(flat & (NC-1));
    int b = (int)(flat >> 21);          // NSEQ*NC = 2^21
    int g = c >> 4;
    float s1 = stats[(b*NG+g)*2], s2 = stats[(b*NG+g)*2+1];
    float mean = s1*inv_cnt;
    float rstd = rsqrtf(s2*inv_cnt - mean*mean + 1e-6f);
    float4 v = *(const float4*)(x + flat);
    float4 sc = *(const float4*)(gsc + c);
    float4 bi = *(const float4*)(gbi + c);
    ushort4 o;
    o.x = f2bf((v.x-mean)*rstd*sc.x + bi.x);
    o.y = f2bf((v.y-mean)*rstd*sc.y + bi.y);
    o.z = f2bf((v.z-mean)*rstd*sc.z + bi.z);
    o.w = f2bf((v.w-mean)*rstd*sc.w + bi.w);
    *(ushort4*)(hn + flat) = o;
  }
}

// transpose 512x512 f32 weight -> bf16 [N][K]
__global__ __launch_bounds__(256) void k_wtrans(const float* __restrict__ w, u16* __restrict__ wt){
  int j = blockIdx.x*256 + threadIdx.x;   // 512*512 total
  int n = j >> 9, k = j & 511;
  wt[j] = f2bf(w[k*512 + n]);
}

// row softmax over S[4096] rows (per-batch), write bf16 P
__global__ __launch_bounds__(256) void k_softmax(const float* __restrict__ S, u16* __restrict__ P){
  int row = blockIdx.x, t = threadIdx.x;
  const float* srow = S + (size_t)row*NSEQ;
  float v[16];
  float mx = -3.4e38f;
  #pragma unroll
  for (int i=0;i<16;i++){ v[i] = srow[t + i*256]; mx = fmaxf(mx, v[i]); }
  #pragma unroll
  for (int o=32;o;o>>=1) mx = fmaxf(mx, __shfl_xor(mx, o));
  __shared__ float sm[4], ss[4];
  if ((t&63)==0) sm[t>>6] = mx;
  __syncthreads();
  mx = fmaxf(fmaxf(sm[0],sm[1]), fmaxf(sm[2],sm[3]));
  float sum = 0.f;
  #pragma unroll
  for (int i=0;i<16;i++){ v[i] = __expf(v[i]-mx); sum += v[i]; }
  #pragma unroll
  for (int o=32;o;o>>=1) sum += __shfl_xor(sum, o);
  if ((t&63)==0) ss[t>>6] = sum;
  __syncthreads();
  float inv = 1.f/(ss[0]+ss[1]+ss[2]+ss[3]);
  u16* pr = P + (size_t)row*NSEQ;
  #pragma unroll
  for (int i=0;i<16;i++) pr[t + i*256] = f2bf(v[i]*inv);
}

// GEMM: C[M,N] = alpha * A[M,K] @ Bt[N,K]^T (+ bias) (+ residual)
// MODE 0: bf16 out [M,N]; MODE 1: bf16 out transposed per-batch (V path);
// MODE 2: f32 out;       MODE 3: f32 out + bias + residual
template<int MODE>
__global__ __launch_bounds__(256) void k_gemm_bt(
    const u16* __restrict__ A, const u16* __restrict__ Bt,
    const float* __restrict__ bias, void* __restrict__ out,
    const float* __restrict__ res, int M, int N, int K, float alpha)
{
  __shared__ u16 As[128*40];   // 32 cols + 8 pad: row stride 80B -> 2-way conflicts only
  __shared__ u16 Bs[128*40];
  const int t = threadIdx.x;
  const int l = t & 63, w = t >> 6;
  const int wr = w >> 1, wc = w & 1;
  const int brow = blockIdx.y*128, bcol = blockIdx.x*128;
  f32x4 acc[4][4] = {};
  const int sr = t >> 2, scc = (t & 3)*8;
  const u16* Ag = A  + (size_t)(brow + sr)*K + scc;
  const u16* Bg = Bt + (size_t)(bcol + sr)*K + scc;
  const int frow = (l & 15), koff = (l >> 4)*8;
  for (int k0 = 0; k0 < K; k0 += 32){
    *(uint4*)&As[sr*40 + scc]      = *(const uint4*)(Ag + k0);
    *(uint4*)&As[(sr+64)*40 + scc] = *(const uint4*)(Ag + (size_t)64*K + k0);
    *(uint4*)&Bs[sr*40 + scc]      = *(const uint4*)(Bg + k0);
    *(uint4*)&Bs[(sr+64)*40 + scc] = *(const uint4*)(Bg + (size_t)64*K + k0);
    __syncthreads();
    bf16x8 afr[4], bfr[4];
    #pragma unroll
    for (int m=0;m<4;m++) afr[m] = *(const bf16x8*)&As[(wr*64 + m*16 + frow)*40 + koff];
    #pragma unroll
    for (int n=0;n<4;n++) bfr[n] = *(const bf16x8*)&Bs[(wc*64 + n*16 + frow)*40 + koff];
    #pragma unroll
    for (int m=0;m<4;m++)
      #pragma unroll
      for (int n=0;n<4;n++)
        acc[m][n] = __builtin_amdgcn_mfma_f32_16x16x32_bf16(afr[m], bfr[n], acc[m][n], 0,0,0);
    __syncthreads();
  }
  #pragma unroll
  for (int m=0;m<4;m++){
    const int row = brow + wr*64 + m*16 + (l>>4)*4;
    #pragma unroll
    for (int n=0;n<4;n++){
      const int col = bcol + wc*64 + n*16 + (l&15);
      const float bv = bias ? bias[col] : 0.f;
      #pragma unroll
      for (int r=0;r<4;r++){
        const int rr = row + r;
        const float vv = alpha*acc[m][n][r] + bv;
        if constexpr (MODE == 0){
          ((u16*)out)[(size_t)rr*N + col] = f2bf(vv);
        } else if constexpr (MODE == 1){
          const int b = rr >> 12, sq = rr & (NSEQ-1);
          ((u16*)out)[((size_t)(b*NC + col) << 12) | (size_t)sq] = f2bf(vv);
        } else if constexpr (MODE == 2){
          ((float*)out)[(size_t)rr*N + col] = vv;
        } else {
          ((float*)out)[(size_t)rr*N + col] = vv + res[(size_t)rr*N + col];
        }
      }
    }
  }
}

extern "C" void kernel_launch(void* const* d_in, const int* in_sizes, int n_in,
                              void* d_out, int out_size, void* d_ws, size_t ws_size,
                              hipStream_t stream){
  const float* x   = (const float*)d_in[0];
  const float* gsc = (const float*)d_in[1];
  const float* gbi = (const float*)d_in[2];
  const float* wq  = (const float*)d_in[3];
  const float* bq  = (const float*)d_in[4];
  const float* wk  = (const float*)d_in[5];
  const float* bk  = (const float*)d_in[6];
  const float* wv  = (const float*)d_in[7];
  const float* bv  = (const float*)d_in[8];
  const float* wo  = (const float*)d_in[9];
  const float* bo  = (const float*)d_in[10];
  float* out = (float*)d_out;

  char* wsp = (char*)d_ws;
  size_t off = 0;
  auto alloc = [&](size_t bytes)->void*{ void* p = wsp + off; off += (bytes + 255) & ~(size_t)255; return p; };
  float* stats = (float*)alloc((size_t)NB*NG*2*sizeof(float));
  u16* hn  = (u16*)alloc((size_t)NM*NC*2);
  u16* wqT = (u16*)alloc((size_t)NC*NC*2);
  u16* wkT = (u16*)alloc((size_t)NC*NC*2);
  u16* wvT = (u16*)alloc((size_t)NC*NC*2);
  u16* woT = (u16*)alloc((size_t)NC*NC*2);
  u16* q   = (u16*)alloc((size_t)NM*NC*2);
  u16* kk  = (u16*)alloc((size_t)NM*NC*2);
  u16* vT  = (u16*)alloc((size_t)NM*NC*2);   // [b][c][seq]
  u16* o   = (u16*)alloc((size_t)NM*NC*2);
  float* S = (float*)alloc((size_t)NSEQ*NSEQ*4);
  u16* P   = (u16*)alloc((size_t)NSEQ*NSEQ*2);

  k_zero<<<1,256,0,stream>>>(stats, NB*NG*2);
  k_gn_stats<<<NB*NG*8,256,0,stream>>>(x, stats);
  k_gn_apply<<<2048,256,0,stream>>>(x, stats, gsc, gbi, hn);
  k_wtrans<<<1024,256,0,stream>>>(wq, wqT);
  k_wtrans<<<1024,256,0,stream>>>(wk, wkT);
  k_wtrans<<<1024,256,0,stream>>>(wv, wvT);
  k_wtrans<<<1024,256,0,stream>>>(wo, woT);

  k_gemm_bt<0><<<dim3(NC/128, NM/128), 256, 0, stream>>>(hn, wqT, bq, q,  nullptr, NM, NC, NC, 1.f);
  k_gemm_bt<0><<<dim3(NC/128, NM/128), 256, 0, stream>>>(hn, wkT, bk, kk, nullptr, NM, NC, NC, 1.f);
  k_gemm_bt<1><<<dim3(NC/128, NM/128), 256, 0, stream>>>(hn, wvT, bv, vT, nullptr, NM, NC, NC, 1.f);

  const float scale = 0.044194173824159216f;  // 512^-0.5
  for (int b = 0; b < NB; b++){
    k_gemm_bt<2><<<dim3(NSEQ/128, NSEQ/128), 256, 0, stream>>>(
        q + (size_t)b*NSEQ*NC, kk + (size_t)b*NSEQ*NC, nullptr, S, nullptr, NSEQ, NSEQ, NC, scale);
    k_softmax<<<NSEQ,256,0,stream>>>(S, P);
    k_gemm_bt<0><<<dim3(NC/128, NSEQ/128), 256, 0, stream>>>(
        P, vT + (size_t)b*NC*NSEQ, nullptr, o + (size_t)b*NSEQ*NC, nullptr, NSEQ, NC, NSEQ, 1.f);
  }
  k_gemm_bt<3><<<dim3(NC/128, NM/128), 256, 0, stream>>>(o, woT, bo, out, x, NM, NC, NC, 1.f);
}

// Round 2
// 374.899 us; speedup vs baseline: 1.8450x; 1.8450x over previous
//
#include <hip/hip_runtime.h>
#include <stdint.h>

typedef unsigned short u16;
typedef __bf16 bf16x8 __attribute__((ext_vector_type(8)));
typedef float f32x4 __attribute__((ext_vector_type(4)));

#define NB 4
#define NC 512
#define NG 32
#define NSEQ 4096
#define NM (NB*NSEQ)

__device__ __forceinline__ u16 f2bf(float f){
  uint32_t u = __builtin_bit_cast(uint32_t, f);
  u += 0x7FFFu + ((u >> 16) & 1u);
  return (u16)(u >> 16);
}

__device__ __forceinline__ void gll16(const void* g, void* l){
  __builtin_amdgcn_global_load_lds(
      (const __attribute__((address_space(1))) void*)g,
      (__attribute__((address_space(3))) void*)l, 16, 0, 0);
}

__global__ void k_zero(float* p, int n){
  int i = blockIdx.x*blockDim.x + threadIdx.x;
  if (i < n) p[i] = 0.f;
}

// GroupNorm partial sums: grid = NB*NG*8 chunks, block 256
__global__ __launch_bounds__(256) void k_gn_stats(const float* __restrict__ x, float* __restrict__ stats){
  int blk = blockIdx.x;
  int ch = blk & 7, bg = blk >> 3;
  int g = bg & (NG-1), b = bg >> 5;
  int t = threadIdx.x;
  const float* base = x + (size_t)b*NSEQ*NC + g*16 + (t&3)*4;
  float s1 = 0.f, s2 = 0.f;
  for (int p = ch*512 + (t>>2); p < (ch+1)*512; p += 64){
    float4 v = *(const float4*)(base + (size_t)p*NC);
    s1 += v.x+v.y+v.z+v.w;
    s2 += v.x*v.x + v.y*v.y + v.z*v.z + v.w*v.w;
  }
  #pragma unroll
  for (int o = 32; o; o >>= 1){ s1 += __shfl_xor(s1, o); s2 += __shfl_xor(s2, o); }
  __shared__ float a1[4], a2[4];
  if ((t & 63) == 0){ a1[t>>6] = s1; a2[t>>6] = s2; }
  __syncthreads();
  if (t == 0){
    atomicAdd(&stats[bg*2+0], a1[0]+a1[1]+a1[2]+a1[3]);
    atomicAdd(&stats[bg*2+1], a2[0]+a2[1]+a2[2]+a2[3]);
  }
}

// normalize + affine, write bf16 hn [NM][NC]
__global__ __launch_bounds__(256) void k_gn_apply(const float* __restrict__ x, const float* __restrict__ stats,
    const float* __restrict__ gsc, const float* __restrict__ gbi, u16* __restrict__ hn){
  const float inv_cnt = 1.f/((float)NSEQ*16.f);
  size_t total = (size_t)NM*NC/4;
  for (size_t i = (size_t)blockIdx.x*blockDim.x + threadIdx.x; i < total; i += (size_t)gridDim.x*blockDim.x){
    size_t flat = i*4;
    int c = (int)(flat & (NC-1));
    int b = (int)(flat >> 21);          // NSEQ*NC = 2^21
    int g = c >> 4;
    float s1 = stats[(b*NG+g)*2], s2 = stats[(b*NG+g)*2+1];
    float mean = s1*inv_cnt;
    float rstd = rsqrtf(s2*inv_cnt - mean*mean + 1e-6f);
    float4 v = *(const float4*)(x + flat);
    float4 sc = *(const float4*)(gsc + c);
    float4 bi = *(const float4*)(gbi + c);
    ushort4 o;
    o.x = f2bf((v.x-mean)*rstd*sc.x + bi.x);
    o.y = f2bf((v.y-mean)*rstd*sc.y + bi.y);
    o.z = f2bf((v.z-mean)*rstd*sc.z + bi.z);
    o.w = f2bf((v.w-mean)*rstd*sc.w + bi.w);
    *(ushort4*)(hn + flat) = o;
  }
}

// transpose all 4 512x512 f32 weights -> bf16 [N][K]; wq/wk/wv concat into wqkvT
__global__ __launch_bounds__(256) void k_wtrans4(const float* __restrict__ wq, const float* __restrict__ wk,
    const float* __restrict__ wv, const float* __restrict__ wo,
    u16* __restrict__ wqkvT, u16* __restrict__ woT){
  int j = blockIdx.x*256 + threadIdx.x;       // 4 * 512*512
  int wsel = j >> 18, r = j & 262143;
  int n = r >> 9, k = r & 511;
  const float* src = wsel==0?wq : wsel==1?wk : wsel==2?wv : wo;
  u16 v = f2bf(src[k*512 + n]);
  if (wsel < 3) wqkvT[(size_t)wsel*262144 + r] = v;
  else          woT[r] = v;
}

// deterministic row sums of P (bf16, unnormalized exp scores)
__global__ __launch_bounds__(256) void k_rowsum(const u16* __restrict__ P, float* __restrict__ sums){
  const int row = blockIdx.x, t = threadIdx.x;
  const u16* pr = P + (size_t)row*NSEQ + t*16;
  uint4 a = *(const uint4*)pr;
  uint4 b = *(const uint4*)(pr + 8);
  uint32_t us[8] = {a.x,a.y,a.z,a.w,b.x,b.y,b.z,b.w};
  float s = 0.f;
  #pragma unroll
  for (int i=0;i<8;i++){
    s += __builtin_bit_cast(float, us[i] << 16);
    s += __builtin_bit_cast(float, us[i] & 0xFFFF0000u);
  }
  #pragma unroll
  for (int o2=32;o2;o2>>=1) s += __shfl_xor(s, o2);
  __shared__ float a4[4];
  if ((t&63)==0) a4[t>>6] = s;
  __syncthreads();
  if (t==0) sums[row] = a4[0]+a4[1]+a4[2]+a4[3];
}

// GEMM (m97 structure): C = alpha * A[M,K] @ B[N,K]^T, global_load_lds staging,
// linear LDS [128][32], 128x128 tile, 4 waves 2x2, 16x16x32 bf16 MFMA.
// MODE 0: QKV projection (N=1536 -> q,k row-major; v transposed per-batch) + bias
// MODE 1: QK^T, out = exp(alpha*acc) as bf16 P   (batched via blockIdx.z)
// MODE 2: PV, out bf16 row-major scaled by 1/rowsum (batched)
// MODE 3: f32 out + bias + residual
template<int MODE>
__global__ __launch_bounds__(256) void k_gemm(
    const u16* __restrict__ A, const u16* __restrict__ B,
    size_t aBatch, size_t bBatch, int K, float alpha,
    void* __restrict__ out0, void* __restrict__ out1, void* __restrict__ out2,
    const float* __restrict__ bias0, const float* __restrict__ bias1, const float* __restrict__ bias2,
    const float* __restrict__ aux0, const float* __restrict__ aux1)
{
  __shared__ u16 As[128*32];
  __shared__ u16 Bs[128*32];
  const int t = threadIdx.x;
  const int l = t & 63, w = t >> 6;
  const int wr = w >> 1, wc = w & 1;
  const int bz = blockIdx.z;
  const int brow = blockIdx.y*128, bcol = blockIdx.x*128;
  f32x4 acc[4][4] = {};
  const u16* Ag = A + (size_t)bz*aBatch + (size_t)(brow + w*16 + (l>>2))*K + (l&3)*8;
  const u16* Bg = B + (size_t)bz*bBatch + (size_t)(bcol + w*16 + (l>>2))*K + (l&3)*8;
  u16* As0 = &As[w*512];  u16* As1 = &As[2048 + w*512];
  u16* Bs0 = &Bs[w*512];  u16* Bs1 = &Bs[2048 + w*512];
  const int frow = l & 15, koff = (l>>4)*8;
  for (int k0 = 0; k0 < K; k0 += 32){
    gll16(Ag + k0, As0);
    gll16(Ag + (size_t)64*K + k0, As1);
    gll16(Bg + k0, Bs0);
    gll16(Bg + (size_t)64*K + k0, Bs1);
    __syncthreads();
    bf16x8 afr[4], bfr[4];
    #pragma unroll
    for (int m=0;m<4;m++) afr[m] = *(const bf16x8*)&As[(wr*64 + m*16 + frow)*32 + koff];
    #pragma unroll
    for (int n=0;n<4;n++) bfr[n] = *(const bf16x8*)&Bs[(wc*64 + n*16 + frow)*32 + koff];
    #pragma unroll
    for (int m=0;m<4;m++)
      #pragma unroll
      for (int n=0;n<4;n++)
        acc[m][n] = __builtin_amdgcn_mfma_f32_16x16x32_bf16(afr[m], bfr[n], acc[m][n], 0,0,0);
    __syncthreads();
  }
  #pragma unroll
  for (int m=0;m<4;m++){
    #pragma unroll
    for (int r=0;r<4;r++){
      const int rr = brow + wr*64 + m*16 + (l>>4)*4 + r;
      float inv = 0.f;
      if constexpr (MODE==2) inv = 1.0f/aux0[bz*NSEQ + rr];
      #pragma unroll
      for (int n=0;n<4;n++){
        const int col = bcol + wc*64 + n*16 + (l&15);
        const float vv = alpha*acc[m][n][r];
        if constexpr (MODE==0){
          const int seg = bcol >> 9;           // block-uniform
          const int colr = col & 511;
          const float* bp = seg==0?bias0:(seg==1?bias1:bias2);
          const float ov = vv + bp[colr];
          if (seg==0)      ((u16*)out0)[(size_t)rr*NC + colr] = f2bf(ov);
          else if (seg==1) ((u16*)out1)[(size_t)rr*NC + colr] = f2bf(ov);
          else { const int b = rr >> 12;
                 ((u16*)out2)[((size_t)(b*NC + colr) << 12) | (size_t)(rr & (NSEQ-1))] = f2bf(ov); }
        } else if constexpr (MODE==1){
          ((u16*)out0)[(size_t)bz*NSEQ*NSEQ + (size_t)rr*NSEQ + col] = f2bf(__expf(vv));
        } else if constexpr (MODE==2){
          ((u16*)out0)[(size_t)bz*NSEQ*NC + (size_t)rr*NC + col] = f2bf(vv*inv);
        } else {
          ((float*)out0)[(size_t)rr*NC + col] = vv + bias0[col] + aux1[(size_t)rr*NC + col];
        }
      }
    }
  }
}

extern "C" void kernel_launch(void* const* d_in, const int* in_sizes, int n_in,
                              void* d_out, int out_size, void* d_ws, size_t ws_size,
                              hipStream_t stream){
  const float* x   = (const float*)d_in[0];
  const float* gsc = (const float*)d_in[1];
  const float* gbi = (const float*)d_in[2];
  const float* wq  = (const float*)d_in[3];
  const float* bq  = (const float*)d_in[4];
  const float* wk  = (const float*)d_in[5];
  const float* bk  = (const float*)d_in[6];
  const float* wv  = (const float*)d_in[7];
  const float* bv  = (const float*)d_in[8];
  const float* wo  = (const float*)d_in[9];
  const float* bo  = (const float*)d_in[10];
  float* out = (float*)d_out;

  char* wsp = (char*)d_ws;
  size_t off = 0;
  auto alloc = [&](size_t bytes)->void*{ void* p = wsp + off; off += (bytes + 255) & ~(size_t)255; return p; };
  float* stats  = (float*)alloc((size_t)NB*NG*2*sizeof(float));
  float* sums   = (float*)alloc((size_t)NM*sizeof(float));
  u16* hn    = (u16*)alloc((size_t)NM*NC*2);
  u16* wqkvT = (u16*)alloc((size_t)3*NC*NC*2);
  u16* woT   = (u16*)alloc((size_t)NC*NC*2);
  u16* q     = (u16*)alloc((size_t)NM*NC*2);
  u16* kk    = (u16*)alloc((size_t)NM*NC*2);
  u16* vT    = (u16*)alloc((size_t)NM*NC*2);   // [b][c][seq]
  u16* o     = (u16*)alloc((size_t)NM*NC*2);
  u16* P     = (u16*)alloc((size_t)NB*NSEQ*NSEQ*2);

  k_zero<<<1,256,0,stream>>>(stats, NB*NG*2);
  k_gn_stats<<<NB*NG*8,256,0,stream>>>(x, stats);
  k_gn_apply<<<2048,256,0,stream>>>(x, stats, gsc, gbi, hn);
  k_wtrans4<<<4096,256,0,stream>>>(wq, wk, wv, wo, wqkvT, woT);

  // fused QKV projection: M=16384, N=1536, K=512
  k_gemm<0><<<dim3(12,128,1),256,0,stream>>>(hn, wqkvT, 0, 0, NC, 1.f,
      q, kk, vT, bq, bk, bv, nullptr, nullptr);

  const float scale = 0.044194173824159216f;  // 512^-0.5
  // QK^T all batches, exp fused: M=N=4096, K=512, z=4
  k_gemm<1><<<dim3(32,32,NB),256,0,stream>>>(q, kk,
      (size_t)NSEQ*NC, (size_t)NSEQ*NC, NC, scale,
      P, nullptr, nullptr, nullptr, nullptr, nullptr, nullptr, nullptr);
  // deterministic row sums of exp-scores
  k_rowsum<<<NM,256,0,stream>>>(P, sums);
  // PV all batches: M=4096, N=512, K=4096, z=4; epilogue scales by 1/rowsum
  k_gemm<2><<<dim3(4,32,NB),256,0,stream>>>(P, vT,
      (size_t)NSEQ*NSEQ, (size_t)NC*NSEQ, NSEQ, 1.f,
      o, nullptr, nullptr, nullptr, nullptr, nullptr, sums, nullptr);
  // output projection + bias + residual: M=16384, N=512, K=512
  k_gemm<3><<<dim3(4,128,1),256,0,stream>>>(o, woT, 0, 0, NC, 1.f,
      out, nullptr, nullptr, bo, nullptr, nullptr, nullptr, x);
}

// Round 3
// 359.519 us; speedup vs baseline: 1.9239x; 1.0428x over previous
//
#include <hip/hip_runtime.h>
#include <stdint.h>

typedef unsigned short u16;
typedef __bf16 bf16x8 __attribute__((ext_vector_type(8)));
typedef float f32x4 __attribute__((ext_vector_type(4)));

#define NB 4
#define NC 512
#define NG 32
#define NSEQ 4096
#define NM (NB*NSEQ)

__device__ __forceinline__ u16 f2bf(float f){
  uint32_t u = __builtin_bit_cast(uint32_t, f);
  u += 0x7FFFu + ((u >> 16) & 1u);
  return (u16)(u >> 16);
}
__device__ __forceinline__ float bfu(uint32_t lo16){  // low u16 -> float
  return __builtin_bit_cast(float, lo16 << 16);
}

__device__ __forceinline__ void gll16(const void* g, void* l){
  __builtin_amdgcn_global_load_lds(
      (const __attribute__((address_space(1))) void*)g,
      (__attribute__((address_space(3))) void*)l, 16, 0, 0);
}

__global__ void k_zero(float* p, int n){
  int i = blockIdx.x*blockDim.x + threadIdx.x;
  if (i < n) p[i] = 0.f;
}

// GroupNorm partial sums: grid = NB*NG*8 chunks, block 256
__global__ __launch_bounds__(256) void k_gn_stats(const float* __restrict__ x, float* __restrict__ stats){
  int blk = blockIdx.x;
  int ch = blk & 7, bg = blk >> 3;
  int g = bg & (NG-1), b = bg >> 5;
  int t = threadIdx.x;
  const float* base = x + (size_t)b*NSEQ*NC + g*16 + (t&3)*4;
  float s1 = 0.f, s2 = 0.f;
  for (int p = ch*512 + (t>>2); p < (ch+1)*512; p += 64){
    float4 v = *(const float4*)(base + (size_t)p*NC);
    s1 += v.x+v.y+v.z+v.w;
    s2 += v.x*v.x + v.y*v.y + v.z*v.z + v.w*v.w;
  }
  #pragma unroll
  for (int o = 32; o; o >>= 1){ s1 += __shfl_xor(s1, o); s2 += __shfl_xor(s2, o); }
  __shared__ float a1[4], a2[4];
  if ((t & 63) == 0){ a1[t>>6] = s1; a2[t>>6] = s2; }
  __syncthreads();
  if (t == 0){
    atomicAdd(&stats[bg*2+0], a1[0]+a1[1]+a1[2]+a1[3]);
    atomicAdd(&stats[bg*2+1], a2[0]+a2[1]+a2[2]+a2[3]);
  }
}

// normalize + affine, write bf16 hn [NM][NC]
__global__ __launch_bounds__(256) void k_gn_apply(const float* __restrict__ x, const float* __restrict__ stats,
    const float* __restrict__ gsc, const float* __restrict__ gbi, u16* __restrict__ hn){
  const float inv_cnt = 1.f/((float)NSEQ*16.f);
  size_t total = (size_t)NM*NC/4;
  for (size_t i = (size_t)blockIdx.x*blockDim.x + threadIdx.x; i < total; i += (size_t)gridDim.x*blockDim.x){
    size_t flat = i*4;
    int c = (int)(flat & (NC-1));
    int b = (int)(flat >> 21);          // NSEQ*NC = 2^21
    int g = c >> 4;
    float s1 = stats[(b*NG+g)*2], s2 = stats[(b*NG+g)*2+1];
    float mean = s1*inv_cnt;
    float rstd = rsqrtf(s2*inv_cnt - mean*mean + 1e-6f);
    float4 v = *(const float4*)(x + flat);
    float4 sc = *(const float4*)(gsc + c);
    float4 bi = *(const float4*)(gbi + c);
    ushort4 o;
    o.x = f2bf((v.x-mean)*rstd*sc.x + bi.x);
    o.y = f2bf((v.y-mean)*rstd*sc.y + bi.y);
    o.z = f2bf((v.z-mean)*rstd*sc.z + bi.z);
    o.w = f2bf((v.w-mean)*rstd*sc.w + bi.w);
    *(ushort4*)(hn + flat) = o;
  }
}

// transpose all 4 512x512 f32 weights -> bf16 [N][K]; wq/wk/wv concat into wqkvT
__global__ __launch_bounds__(256) void k_wtrans4(const float* __restrict__ wq, const float* __restrict__ wk,
    const float* __restrict__ wv, const float* __restrict__ wo,
    u16* __restrict__ wqkvT, u16* __restrict__ woT){
  int j = blockIdx.x*256 + threadIdx.x;       // 4 * 512*512
  int wsel = j >> 18, r = j & 262143;
  int n = r >> 9, k = r & 511;
  const float* src = wsel==0?wq : wsel==1?wk : wsel==2?wv : wo;
  u16 v = f2bf(src[k*512 + n]);
  if (wsel < 3) wqkvT[(size_t)wsel*262144 + r] = v;
  else          woT[r] = v;
}

// reduce 64 chunk-partials per row -> sums[row]; one wave per row
__global__ __launch_bounds__(256) void k_sumred(const float* __restrict__ part, float* __restrict__ sums){
  int row = blockIdx.x*4 + (threadIdx.x >> 6);
  int l = threadIdx.x & 63;
  float s = part[(size_t)row*64 + l];
  #pragma unroll
  for (int o = 32; o; o >>= 1) s += __shfl_xor(s, o);
  if (l == 0) sums[row] = s;
}

// combine 2 split-K bf16 partials, scale by 1/rowsum, write bf16 o
__global__ __launch_bounds__(256) void k_pvred(const u16* __restrict__ op, const float* __restrict__ sums,
    u16* __restrict__ o){
  size_t i = ((size_t)blockIdx.x*256 + threadIdx.x)*8;
  int row = (int)(i >> 9);
  float inv = 1.f/sums[row];
  uint4 a = *(const uint4*)(op + i);
  uint4 b = *(const uint4*)(op + (size_t)NM*NC + i);
  uint32_t pa[4] = {a.x,a.y,a.z,a.w}, pb[4] = {b.x,b.y,b.z,b.w};
  uint32_t r[4];
  #pragma unroll
  for (int j=0;j<4;j++){
    float lo = (bfu(pa[j] & 0xFFFFu) + bfu(pb[j] & 0xFFFFu)) * inv;
    float hi = (__builtin_bit_cast(float, pa[j] & 0xFFFF0000u) +
                __builtin_bit_cast(float, pb[j] & 0xFFFF0000u)) * inv;
    r[j] = (uint32_t)f2bf(lo) | ((uint32_t)f2bf(hi) << 16);
  }
  *(uint4*)(o + i) = make_uint4(r[0], r[1], r[2], r[3]);
}

// GEMM (m97 structure): C = alpha * A[.,lda] @ B[.,ldb]^T over Klen, global_load_lds
// staging, linear LDS [128][32], 128x128 tile, 4 waves 2x2, 16x16x32 bf16 MFMA.
// Bijective XCD swizzle (m204 simple form; all grids have nwg%8==0).
// MODE 0: QKV projection (N=1536 -> q,k row-major; v transposed per-batch) + bias
// MODE 1: QK^T: out = exp(alpha*acc) bf16 P + per-(row,64col-chunk) f32 partial sums
// MODE 3: f32 out + bias + residual
// MODE 4: PV split-K: z encodes (b, split); bf16 partial out (no scaling)
template<int MODE>
__global__ __launch_bounds__(256) void k_gemm(
    const u16* __restrict__ A, const u16* __restrict__ B,
    size_t aBatch, size_t bBatch, int lda, int ldb, int Klen, float alpha,
    void* __restrict__ out0, void* __restrict__ out1, void* __restrict__ out2,
    const float* __restrict__ bias0, const float* __restrict__ bias1, const float* __restrict__ bias2,
    const float* __restrict__ aux1)
{
  __shared__ u16 As[128*32];
  __shared__ u16 Bs[128*32];
  const int t = threadIdx.x;
  const int l = t & 63, w = t >> 6;
  const int wr = w >> 1, wc = w & 1;
  // --- XCD-aware bijective remap of (bx,by,bz) ---
  const int nx = gridDim.x, ny = gridDim.y;
  int f = ((int)blockIdx.z*ny + (int)blockIdx.y)*nx + (int)blockIdx.x;
  const int nwg = nx*ny*(int)gridDim.z;
  f = (f & 7)*(nwg >> 3) + (f >> 3);
  const int bx = f % nx; const int t2 = f / nx;
  const int by = t2 % ny; const int bz = t2 / ny;
  // batch / split decode
  int bb = 0, kOff = 0;
  if constexpr (MODE == 1) bb = bz;
  if constexpr (MODE == 4){ bb = bz & 3; kOff = (bz >> 2)*(NSEQ/2); }
  const int brow = by*128, bcol = bx*128;
  f32x4 acc[4][4] = {};
  const u16* Ag = A + (size_t)bb*aBatch + (size_t)(brow + w*16 + (l>>2))*lda + (l&3)*8 + kOff;
  const u16* Bg = B + (size_t)bb*bBatch + (size_t)(bcol + w*16 + (l>>2))*ldb + (l&3)*8 + kOff;
  u16* As0 = &As[w*512];  u16* As1 = &As[2048 + w*512];
  u16* Bs0 = &Bs[w*512];  u16* Bs1 = &Bs[2048 + w*512];
  const int frow = l & 15, koff = (l>>4)*8;
  for (int k0 = 0; k0 < Klen; k0 += 32){
    gll16(Ag + k0, As0);
    gll16(Ag + (size_t)64*lda + k0, As1);
    gll16(Bg + k0, Bs0);
    gll16(Bg + (size_t)64*ldb + k0, Bs1);
    __syncthreads();
    bf16x8 afr[4], bfr[4];
    #pragma unroll
    for (int m=0;m<4;m++) afr[m] = *(const bf16x8*)&As[(wr*64 + m*16 + frow)*32 + koff];
    #pragma unroll
    for (int n=0;n<4;n++) bfr[n] = *(const bf16x8*)&Bs[(wc*64 + n*16 + frow)*32 + koff];
    #pragma unroll
    for (int m=0;m<4;m++)
      #pragma unroll
      for (int n=0;n<4;n++)
        acc[m][n] = __builtin_amdgcn_mfma_f32_16x16x32_bf16(afr[m], bfr[n], acc[m][n], 0,0,0);
    __syncthreads();
  }
  #pragma unroll
  for (int m=0;m<4;m++){
    #pragma unroll
    for (int r=0;r<4;r++){
      const int rr = brow + wr*64 + m*16 + (l>>4)*4 + r;
      float rs = 0.f;
      #pragma unroll
      for (int n=0;n<4;n++){
        const int col = bcol + wc*64 + n*16 + (l&15);
        const float vv = alpha*acc[m][n][r];
        if constexpr (MODE==0){
          const int seg = bcol >> 9;           // block-uniform
          const int colr = col & 511;
          const float* bp = seg==0?bias0:(seg==1?bias1:bias2);
          const float ov = vv + bp[colr];
          if (seg==0)      ((u16*)out0)[(size_t)rr*NC + colr] = f2bf(ov);
          else if (seg==1) ((u16*)out1)[(size_t)rr*NC + colr] = f2bf(ov);
          else { const int b = rr >> 12;
                 ((u16*)out2)[((size_t)(b*NC + colr) << 12) | (size_t)(rr & (NSEQ-1))] = f2bf(ov); }
        } else if constexpr (MODE==1){
          const u16 pv = f2bf(__expf(vv));
          ((u16*)out0)[(size_t)bb*NSEQ*NSEQ + (size_t)rr*NSEQ + col] = pv;
          rs += bfu(pv);
        } else if constexpr (MODE==4){
          const int sp = bz >> 2;
          ((u16*)out0)[((size_t)sp*NM + (size_t)bb*NSEQ + rr)*NC + col] = f2bf(vv);
        } else {
          ((float*)out0)[(size_t)rr*NC + col] = vv + bias0[col] + aux1[(size_t)rr*NC + col];
        }
      }
      if constexpr (MODE==1){
        // reduce across the 16-lane col group -> full 64-col wave partial for this row
        rs += __shfl_xor(rs, 1); rs += __shfl_xor(rs, 2);
        rs += __shfl_xor(rs, 4); rs += __shfl_xor(rs, 8);
        if ((l & 15) == 0)
          ((float*)out1)[((size_t)bb*NSEQ + rr)*64 + bx*2 + wc] = rs;
      }
    }
  }
}

extern "C" void kernel_launch(void* const* d_in, const int* in_sizes, int n_in,
                              void* d_out, int out_size, void* d_ws, size_t ws_size,
                              hipStream_t stream){
  const float* x   = (const float*)d_in[0];
  const float* gsc = (const float*)d_in[1];
  const float* gbi = (const float*)d_in[2];
  const float* wq  = (const float*)d_in[3];
  const float* bq  = (const float*)d_in[4];
  const float* wk  = (const float*)d_in[5];
  const float* bk  = (const float*)d_in[6];
  const float* wv  = (const float*)d_in[7];
  const float* bv  = (const float*)d_in[8];
  const float* wo  = (const float*)d_in[9];
  const float* bo  = (const float*)d_in[10];
  float* out = (float*)d_out;

  char* wsp = (char*)d_ws;
  size_t off = 0;
  auto alloc = [&](size_t bytes)->void*{ void* p = wsp + off; off += (bytes + 255) & ~(size_t)255; return p; };
  float* stats   = (float*)alloc((size_t)NB*NG*2*sizeof(float));
  float* sums    = (float*)alloc((size_t)NM*sizeof(float));
  float* partsum = (float*)alloc((size_t)NM*64*sizeof(float));
  u16* hn    = (u16*)alloc((size_t)NM*NC*2);
  u16* wqkvT = (u16*)alloc((size_t)3*NC*NC*2);
  u16* woT   = (u16*)alloc((size_t)NC*NC*2);
  u16* q     = (u16*)alloc((size_t)NM*NC*2);
  u16* kk    = (u16*)alloc((size_t)NM*NC*2);   // q,kk contiguous (each 16 MiB, 256B-aligned)
  u16* vT    = (u16*)alloc((size_t)NM*NC*2);   // [b][c][seq]
  u16* o     = (u16*)alloc((size_t)NM*NC*2);
  u16* P     = (u16*)alloc((size_t)NB*NSEQ*NSEQ*2);
  u16* opart = q;  // alias: PV split-K partials [2][NM][NC] over dead q+kk (exactly 32 MiB)

  k_zero<<<1,256,0,stream>>>(stats, NB*NG*2);
  k_gn_stats<<<NB*NG*8,256,0,stream>>>(x, stats);
  k_gn_apply<<<2048,256,0,stream>>>(x, stats, gsc, gbi, hn);
  k_wtrans4<<<4096,256,0,stream>>>(wq, wk, wv, wo, wqkvT, woT);

  // fused QKV projection: M=16384, N=1536, K=512
  k_gemm<0><<<dim3(12,128,1),256,0,stream>>>(hn, wqkvT, 0, 0, NC, NC, NC, 1.f,
      q, kk, vT, bq, bk, bv, nullptr);

  const float scale = 0.044194173824159216f;  // 512^-0.5
  // QK^T all batches, exp + chunk row-partials fused: M=N=4096, K=512, z=4
  k_gemm<1><<<dim3(32,32,NB),256,0,stream>>>(q, kk,
      (size_t)NSEQ*NC, (size_t)NSEQ*NC, NC, NC, NC, scale,
      P, partsum, nullptr, nullptr, nullptr, nullptr, nullptr);
  // rowsum = reduce 64 chunk partials per row
  k_sumred<<<NM/4,256,0,stream>>>(partsum, sums);
  // PV split-K=2, all batches: M=4096, N=512, Klen=2048, z = b(4) x split(2)
  k_gemm<4><<<dim3(4,32,8),256,0,stream>>>(P, vT,
      (size_t)NSEQ*NSEQ, (size_t)NC*NSEQ, NSEQ, NSEQ, NSEQ/2, 1.f,
      opart, nullptr, nullptr, nullptr, nullptr, nullptr, nullptr);
  // combine partials + 1/rowsum -> o (bf16)
  k_pvred<<<NM*NC/8/256,256,0,stream>>>(opart, sums, o);
  // output projection + bias + residual: M=16384, N=512, K=512
  k_gemm<3><<<dim3(4,128,1),256,0,stream>>>(o, woT, 0, 0, NC, NC, NC, 1.f,
      out, nullptr, nullptr, bo, nullptr, nullptr, x);
}

// Round 4
// 312.461 us; speedup vs baseline: 2.2137x; 1.1506x over previous
//
#include <hip/hip_runtime.h>
#include <stdint.h>

typedef unsigned short u16;
typedef __bf16 bf16x8 __attribute__((ext_vector_type(8)));
typedef float f32x4 __attribute__((ext_vector_type(4)));

#define NB 4
#define NC 512
#define NG 32
#define NSEQ 4096
#define NM (NB*NSEQ)

#define MFMA_(a,b,c) __builtin_amdgcn_mfma_f32_16x16x32_bf16(a,b,c,0,0,0)

__device__ __forceinline__ u16 f2bf(float f){
  uint32_t u = __builtin_bit_cast(uint32_t, f);
  u += 0x7FFFu + ((u >> 16) & 1u);
  return (u16)(u >> 16);
}
__device__ __forceinline__ float bfu(uint32_t lo16){
  return __builtin_bit_cast(float, lo16 << 16);
}

__device__ __forceinline__ void gll16(const void* g, void* l){
  __builtin_amdgcn_global_load_lds(
      (const __attribute__((address_space(1))) void*)g,
      (__attribute__((address_space(3))) void*)l, 16, 0, 0);
}

__global__ void k_zero(float* p, int n){
  int i = blockIdx.x*blockDim.x + threadIdx.x;
  if (i < n) p[i] = 0.f;
}

__global__ __launch_bounds__(256) void k_gn_stats(const float* __restrict__ x, float* __restrict__ stats){
  int blk = blockIdx.x;
  int ch = blk & 7, bg = blk >> 3;
  int g = bg & (NG-1), b = bg >> 5;
  int t = threadIdx.x;
  const float* base = x + (size_t)b*NSEQ*NC + g*16 + (t&3)*4;
  float s1 = 0.f, s2 = 0.f;
  for (int p = ch*512 + (t>>2); p < (ch+1)*512; p += 64){
    float4 v = *(const float4*)(base + (size_t)p*NC);
    s1 += v.x+v.y+v.z+v.w;
    s2 += v.x*v.x + v.y*v.y + v.z*v.z + v.w*v.w;
  }
  #pragma unroll
  for (int o = 32; o; o >>= 1){ s1 += __shfl_xor(s1, o); s2 += __shfl_xor(s2, o); }
  __shared__ float a1[4], a2[4];
  if ((t & 63) == 0){ a1[t>>6] = s1; a2[t>>6] = s2; }
  __syncthreads();
  if (t == 0){
    atomicAdd(&stats[bg*2+0], a1[0]+a1[1]+a1[2]+a1[3]);
    atomicAdd(&stats[bg*2+1], a2[0]+a2[1]+a2[2]+a2[3]);
  }
}

__global__ __launch_bounds__(256) void k_gn_apply(const float* __restrict__ x, const float* __restrict__ stats,
    const float* __restrict__ gsc, const float* __restrict__ gbi, u16* __restrict__ hn){
  const float inv_cnt = 1.f/((float)NSEQ*16.f);
  size_t total = (size_t)NM*NC/4;
  for (size_t i = (size_t)blockIdx.x*blockDim.x + threadIdx.x; i < total; i += (size_t)gridDim.x*blockDim.x){
    size_t flat = i*4;
    int c = (int)(flat & (NC-1));
    int b = (int)(flat >> 21);
    int g = c >> 4;
    float s1 = stats[(b*NG+g)*2], s2 = stats[(b*NG+g)*2+1];
    float mean = s1*inv_cnt;
    float rstd = rsqrtf(s2*inv_cnt - mean*mean + 1e-6f);
    float4 v = *(const float4*)(x + flat);
    float4 sc = *(const float4*)(gsc + c);
    float4 bi = *(const float4*)(gbi + c);
    ushort4 o;
    o.x = f2bf((v.x-mean)*rstd*sc.x + bi.x);
    o.y = f2bf((v.y-mean)*rstd*sc.y + bi.y);
    o.z = f2bf((v.z-mean)*rstd*sc.z + bi.z);
    o.w = f2bf((v.w-mean)*rstd*sc.w + bi.w);
    *(ushort4*)(hn + flat) = o;
  }
}

__global__ __launch_bounds__(256) void k_wtrans4(const float* __restrict__ wq, const float* __restrict__ wk,
    const float* __restrict__ wv, const float* __restrict__ wo,
    u16* __restrict__ wqkvT, u16* __restrict__ woT){
  int j = blockIdx.x*256 + threadIdx.x;
  int wsel = j >> 18, r = j & 262143;
  int n = r >> 9, k = r & 511;
  const float* src = wsel==0?wq : wsel==1?wk : wsel==2?wv : wo;
  u16 v = f2bf(src[k*512 + n]);
  if (wsel < 3) wqkvT[(size_t)wsel*262144 + r] = v;
  else          woT[r] = v;
}

__global__ __launch_bounds__(256) void k_sumred(const float* __restrict__ part, float* __restrict__ sums){
  int row = blockIdx.x*4 + (threadIdx.x >> 6);
  int l = threadIdx.x & 63;
  float s = part[(size_t)row*64 + l];
  #pragma unroll
  for (int o = 32; o; o >>= 1) s += __shfl_xor(s, o);
  if (l == 0) sums[row] = s;
}

__global__ __launch_bounds__(256) void k_pvred(const u16* __restrict__ op, const float* __restrict__ sums,
    u16* __restrict__ o){
  size_t i = ((size_t)blockIdx.x*256 + threadIdx.x)*8;
  int row = (int)(i >> 9);
  float inv = 1.f/sums[row];
  uint4 a = *(const uint4*)(op + i);
  uint4 b = *(const uint4*)(op + (size_t)NM*NC + i);
  uint32_t pa[4] = {a.x,a.y,a.z,a.w}, pb[4] = {b.x,b.y,b.z,b.w};
  uint32_t r[4];
  #pragma unroll
  for (int j=0;j<4;j++){
    float lo = (bfu(pa[j] & 0xFFFFu) + bfu(pb[j] & 0xFFFFu)) * inv;
    float hi = (__builtin_bit_cast(float, pa[j] & 0xFFFF0000u) +
                __builtin_bit_cast(float, pb[j] & 0xFFFF0000u)) * inv;
    r[j] = (uint32_t)f2bf(lo) | ((uint32_t)f2bf(hi) << 16);
  }
  *(uint4*)(o + i) = make_uint4(r[0], r[1], r[2], r[3]);
}

// ---------------- 256x256 8-phase GEMM (T1+T2+T3+T4+T5) ----------------
// C = alpha * A[.,lda] @ B[.,ldb]^T over Klen. 512 thr = 8 waves (2Mx4N),
// BK=64, LDS 128KB: 2 buf x {A,B} x 2 half-tiles [128][64] bf16, XOR-swizzled.
// MODE 0: QKV (q,k row-major; v transposed per-batch) + bias
// MODE 1: QK^T: P = exp(alpha*acc) bf16 + per-(row,64col) f32 partial sums
// MODE 3: f32 out + bias + residual
// MODE 4: PV split-K: z=(split,b); bf16 partial out
#define PH_A  { __builtin_amdgcn_sched_barrier(0); __builtin_amdgcn_s_barrier(); \
  asm volatile("s_waitcnt lgkmcnt(0)" ::: "memory"); __builtin_amdgcn_sched_barrier(0); \
  __builtin_amdgcn_s_setprio(1); }
#define PH_B  { __builtin_amdgcn_s_setprio(0); __builtin_amdgcn_sched_barrier(0); \
  __builtin_amdgcn_s_barrier(); }
#define PH_BV { __builtin_amdgcn_s_setprio(0); __builtin_amdgcn_sched_barrier(0); \
  asm volatile("s_waitcnt vmcnt(8)" ::: "memory"); __builtin_amdgcn_s_barrier(); }

template<int MODE>
__global__ __launch_bounds__(512, 2) void k_gemm8(
    const u16* __restrict__ A, const u16* __restrict__ B,
    size_t aBatch, size_t bBatch, int lda_, int ldb_, int Klen, float alpha,
    void* __restrict__ out0, void* __restrict__ out1, void* __restrict__ out2,
    const float* __restrict__ bias0, const float* __restrict__ bias1, const float* __restrict__ bias2,
    const float* __restrict__ aux1)
{
  __shared__ u16 LDS[65536];   // 128 KiB
  const size_t lda = lda_, ldb = ldb_;
  const int t = threadIdx.x;
  const int l = t & 63, w = t >> 6;
  const int wr = w >> 2, wc = w & 3;
  const int frow = l & 15, kq = l >> 4;
  // XCD-aware bijective remap
  const int nx = gridDim.x, ny = gridDim.y;
  int f = ((int)blockIdx.z*ny + (int)blockIdx.y)*nx + (int)blockIdx.x;
  const int nwg = nx*ny*(int)gridDim.z;
  f = (f & 7)*(nwg >> 3) + (f >> 3);
  const int bx = f % nx; const int t2 = f / nx;
  const int by = t2 % ny; const int bz = t2 / ny;
  int bb = 0, kOff = 0;
  if constexpr (MODE == 1) bb = bz;
  if constexpr (MODE == 4){ bb = bz & 3; kOff = (bz >> 2)*(NSEQ/2); }
  const int brow = by*256, bcol = bx*256;

  f32x4 acc[8][4] = {};
  // staging: thread t covers row (t>>3) of a 64-row slab, 16B at pre-swizzled k
  const int kswz = 8*((t&7) ^ ((t>>3)&7));
  const u16* Ast = A + (size_t)bb*aBatch + (size_t)(brow + (t>>3))*lda + kOff + kswz;
  const u16* Bst = B + (size_t)bb*bBatch + (size_t)(bcol + (t>>3))*ldb + kOff + kswz;
  char* Lb = (char*)LDS;
  char* stD = Lb + t*16;

  auto stage = [&](int buf, int isB, int half, int kt){
    const u16* s = (isB ? Bst : Ast) + (size_t)(half*128)*(isB?ldb:lda) + (size_t)kt*64;
    char* d = stD + buf*65536 + isB*32768 + half*16384;
    gll16(s, d);
    gll16(s + (size_t)64*(isB?ldb:lda), d + 8192);
  };
  auto ldA = [&](int buf, int quad, bf16x8* dst){
    const char* base = Lb + buf*65536 + wr*16384;
    #pragma unroll
    for (int mf=0; mf<4; mf++)
      #pragma unroll
      for (int ks=0; ks<2; ks++){
        int rl = quad*64 + mf*16 + frow;
        int byte = (rl*128 + ks*64 + kq*16) ^ ((rl&7)<<4);
        dst[mf*2+ks] = *(const bf16x8*)(base + byte);
      }
  };
  auto ldB = [&](int buf, int qc, bf16x8* dst){
    const char* base = Lb + buf*65536 + 32768 + (wc>>1)*16384;
    #pragma unroll
    for (int nf=0; nf<2; nf++)
      #pragma unroll
      for (int ks=0; ks<2; ks++){
        int rl = (wc&1)*64 + qc*32 + nf*16 + frow;
        int byte = (rl*128 + ks*64 + kq*16) ^ ((rl&7)<<4);
        dst[nf*2+ks] = *(const bf16x8*)(base + byte);
      }
  };
  auto quad = [&](int qr, int qc, const bf16x8* af, const bf16x8* bf){
    #pragma unroll
    for (int mf=0; mf<4; mf++)
      #pragma unroll
      for (int nf=0; nf<2; nf++)
        #pragma unroll
        for (int ks=0; ks<2; ks++)
          acc[qr*4+mf][qc*2+nf] = MFMA_(af[mf*2+ks], bf[nf*2+ks], acc[qr*4+mf][qc*2+nf]);
  };

  bf16x8 af[8], b0[4], b1[4];
  const int NT = Klen >> 6;
  // prologue: tile 0 -> buf0, tile 1 -> buf1
  stage(0,0,0,0); stage(0,0,1,0); stage(0,1,0,0); stage(0,1,1,0);
  stage(1,0,0,1); stage(1,0,1,1); stage(1,1,0,1); stage(1,1,1,1);
  asm volatile("s_waitcnt vmcnt(8)" ::: "memory");
  __builtin_amdgcn_s_barrier();

  for (int i = 0; i < (NT>>1); i++){
    const int st0 = (2*i+2 < NT) ? 2*i+2 : NT-1;
    const int st1 = (2*i+3 < NT) ? 2*i+3 : NT-1;
    // P1 (r0,c0)
    ldA(0,0,af); ldB(0,0,b0);
    PH_A; quad(0,0,af,b0); PH_B;
    // P2 (r0,c1)
    ldB(0,1,b1);
    PH_A; quad(0,1,af,b1); PH_B;
    // P3 (r1,c0): buf0.B dead after P2 -> stage next B
    ldA(0,1,af);
    stage(0,1,0,st0); stage(0,1,1,st0);
    PH_A; quad(1,0,af,b0); PH_B;
    // P4 (r1,c1): buf0.A dead after P3 -> stage next A; certify buf1 landed
    stage(0,0,0,st0); stage(0,0,1,st0);
    PH_A; quad(1,1,af,b1); PH_BV;
    // P5 (r0,c0) on buf1
    ldA(1,0,af); ldB(1,0,b0);
    PH_A; quad(0,0,af,b0); PH_B;
    // P6 (r0,c1)
    ldB(1,1,b1);
    PH_A; quad(0,1,af,b1); PH_B;
    // P7 (r1,c0): stage buf1.B
    ldA(1,1,af);
    stage(1,1,0,st1); stage(1,1,1,st1);
    PH_A; quad(1,0,af,b0); PH_B;
    // P8 (r1,c1): stage buf1.A; certify buf0 landed
    stage(1,0,0,st1); stage(1,0,1,st1);
    PH_A; quad(1,1,af,b1); PH_BV;
  }

  // epilogue
  #pragma unroll
  for (int m=0;m<8;m++){
    #pragma unroll
    for (int r=0;r<4;r++){
      const int rr = brow + wr*128 + m*16 + kq*4 + r;
      float rs = 0.f;
      #pragma unroll
      for (int n=0;n<4;n++){
        const int col = bcol + wc*64 + n*16 + frow;
        const float vv = alpha*acc[m][n][r];
        if constexpr (MODE==0){
          const int seg = bcol >> 9;
          const int colr = col & 511;
          const float* bp = seg==0?bias0:(seg==1?bias1:bias2);
          const float ov = vv + bp[colr];
          if (seg==0)      ((u16*)out0)[(size_t)rr*NC + colr] = f2bf(ov);
          else if (seg==1) ((u16*)out1)[(size_t)rr*NC + colr] = f2bf(ov);
          else { const int b = rr >> 12;
                 ((u16*)out2)[((size_t)(b*NC + colr) << 12) | (size_t)(rr & (NSEQ-1))] = f2bf(ov); }
        } else if constexpr (MODE==1){
          const u16 pv = f2bf(__expf(vv));
          ((u16*)out0)[(size_t)bb*NSEQ*NSEQ + (size_t)rr*NSEQ + col] = pv;
          rs += bfu(pv);
        } else if constexpr (MODE==4){
          const int sp = bz >> 2;
          ((u16*)out0)[((size_t)sp*NM + (size_t)bb*NSEQ + rr)*NC + col] = f2bf(vv);
        } else {
          ((float*)out0)[(size_t)rr*NC + col] = vv + bias0[col] + aux1[(size_t)rr*NC + col];
        }
      }
      if constexpr (MODE==1){
        rs += __shfl_xor(rs, 1); rs += __shfl_xor(rs, 2);
        rs += __shfl_xor(rs, 4); rs += __shfl_xor(rs, 8);
        if (frow == 0)
          ((float*)out1)[((size_t)bb*NSEQ + rr)*64 + bx*4 + wc] = rs;
      }
    }
  }
}

extern "C" void kernel_launch(void* const* d_in, const int* in_sizes, int n_in,
                              void* d_out, int out_size, void* d_ws, size_t ws_size,
                              hipStream_t stream){
  const float* x   = (const float*)d_in[0];
  const float* gsc = (const float*)d_in[1];
  const float* gbi = (const float*)d_in[2];
  const float* wq  = (const float*)d_in[3];
  const float* bq  = (const float*)d_in[4];
  const float* wk  = (const float*)d_in[5];
  const float* bk  = (const float*)d_in[6];
  const float* wv  = (const float*)d_in[7];
  const float* bv  = (const float*)d_in[8];
  const float* wo  = (const float*)d_in[9];
  const float* bo  = (const float*)d_in[10];
  float* out = (float*)d_out;

  char* wsp = (char*)d_ws;
  size_t off = 0;
  auto alloc = [&](size_t bytes)->void*{ void* p = wsp + off; off += (bytes + 255) & ~(size_t)255; return p; };
  float* stats   = (float*)alloc((size_t)NB*NG*2*sizeof(float));
  float* sums    = (float*)alloc((size_t)NM*sizeof(float));
  float* partsum = (float*)alloc((size_t)NM*64*sizeof(float));
  u16* hn    = (u16*)alloc((size_t)NM*NC*2);
  u16* wqkvT = (u16*)alloc((size_t)3*NC*NC*2);
  u16* woT   = (u16*)alloc((size_t)NC*NC*2);
  u16* q     = (u16*)alloc((size_t)NM*NC*2);
  u16* kk    = (u16*)alloc((size_t)NM*NC*2);
  u16* vT    = (u16*)alloc((size_t)NM*NC*2);
  u16* o     = (u16*)alloc((size_t)NM*NC*2);
  u16* P     = (u16*)alloc((size_t)NB*NSEQ*NSEQ*2);
  u16* opart = q;  // PV split-K partials [2][NM][NC] alias dead q+kk (32 MiB)

  k_zero<<<1,256,0,stream>>>(stats, NB*NG*2);
  k_gn_stats<<<NB*NG*8,256,0,stream>>>(x, stats);
  k_gn_apply<<<2048,256,0,stream>>>(x, stats, gsc, gbi, hn);
  k_wtrans4<<<4096,256,0,stream>>>(wq, wk, wv, wo, wqkvT, woT);

  // QKV projection: M=16384, N=1536, K=512
  k_gemm8<0><<<dim3(6,64,1),512,0,stream>>>(hn, wqkvT, 0, 0, NC, NC, NC, 1.f,
      q, kk, vT, bq, bk, bv, nullptr);

  const float scale = 0.044194173824159216f;  // 512^-0.5
  // QK^T all batches + exp + row partials: M=N=4096, K=512, z=4
  k_gemm8<1><<<dim3(16,16,NB),512,0,stream>>>(q, kk,
      (size_t)NSEQ*NC, (size_t)NSEQ*NC, NC, NC, NC, scale,
      P, partsum, nullptr, nullptr, nullptr, nullptr, nullptr);
  k_sumred<<<NM/4,256,0,stream>>>(partsum, sums);
  // PV split-K=2: M=4096, N=512, Klen=2048, z=(split,b) -> 256 blocks
  k_gemm8<4><<<dim3(2,16,8),512,0,stream>>>(P, vT,
      (size_t)NSEQ*NSEQ, (size_t)NC*NSEQ, NSEQ, NSEQ, NSEQ/2, 1.f,
      opart, nullptr, nullptr, nullptr, nullptr, nullptr, nullptr);
  k_pvred<<<NM*NC/8/256,256,0,stream>>>(opart, sums, o);
  // output projection + bias + residual: M=16384, N=512, K=512
  k_gemm8<3><<<dim3(2,64,1),512,0,stream>>>(o, woT, 0, 0, NC, NC, NC, 1.f,
      out, nullptr, nullptr, bo, nullptr, nullptr, x);
}

// Round 5
// 283.553 us; speedup vs baseline: 2.4393x; 1.1019x over previous
//
#include <hip/hip_runtime.h>
#include <stdint.h>

typedef unsigned short u16;
typedef __bf16 bf16x8 __attribute__((ext_vector_type(8)));
typedef float f32x4 __attribute__((ext_vector_type(4)));

#define NB 4
#define NC 512
#define NG 32
#define NSEQ 4096
#define NM (NB*NSEQ)

#define MFMA_(a,b,c) __builtin_amdgcn_mfma_f32_16x16x32_bf16(a,b,c,0,0,0)
// LDS row swizzle: works for stride-1 (A-frag) and stride-4 (B-frag) row access
#define SWZ(rl) (((((rl) ^ ((rl)>>2)) & 7)) << 4)

__device__ __forceinline__ u16 f2bf(float f){
  uint32_t u = __builtin_bit_cast(uint32_t, f);
  u += 0x7FFFu + ((u >> 16) & 1u);
  return (u16)(u >> 16);
}
__device__ __forceinline__ float bfu(uint32_t lo16){
  return __builtin_bit_cast(float, lo16 << 16);
}
__device__ __forceinline__ uint32_t pk2(float a, float b){
  return (uint32_t)f2bf(a) | ((uint32_t)f2bf(b) << 16);
}

__device__ __forceinline__ void gll16(const void* g, void* l){
  __builtin_amdgcn_global_load_lds(
      (const __attribute__((address_space(1))) void*)g,
      (__attribute__((address_space(3))) void*)l, 16, 0, 0);
}

__global__ void k_zero(float* p, int n){
  int i = blockIdx.x*blockDim.x + threadIdx.x;
  if (i < n) p[i] = 0.f;
}

__global__ __launch_bounds__(256) void k_gn_stats(const float* __restrict__ x, float* __restrict__ stats){
  int blk = blockIdx.x;
  int ch = blk & 7, bg = blk >> 3;
  int g = bg & (NG-1), b = bg >> 5;
  int t = threadIdx.x;
  const float* base = x + (size_t)b*NSEQ*NC + g*16 + (t&3)*4;
  float s1 = 0.f, s2 = 0.f;
  for (int p = ch*512 + (t>>2); p < (ch+1)*512; p += 64){
    float4 v = *(const float4*)(base + (size_t)p*NC);
    s1 += v.x+v.y+v.z+v.w;
    s2 += v.x*v.x + v.y*v.y + v.z*v.z + v.w*v.w;
  }
  #pragma unroll
  for (int o = 32; o; o >>= 1){ s1 += __shfl_xor(s1, o); s2 += __shfl_xor(s2, o); }
  __shared__ float a1[4], a2[4];
  if ((t & 63) == 0){ a1[t>>6] = s1; a2[t>>6] = s2; }
  __syncthreads();
  if (t == 0){
    atomicAdd(&stats[bg*2+0], a1[0]+a1[1]+a1[2]+a1[3]);
    atomicAdd(&stats[bg*2+1], a2[0]+a2[1]+a2[2]+a2[3]);
  }
}

__global__ __launch_bounds__(256) void k_gn_apply(const float* __restrict__ x, const float* __restrict__ stats,
    const float* __restrict__ gsc, const float* __restrict__ gbi, u16* __restrict__ hn){
  const float inv_cnt = 1.f/((float)NSEQ*16.f);
  size_t total = (size_t)NM*NC/4;
  for (size_t i = (size_t)blockIdx.x*blockDim.x + threadIdx.x; i < total; i += (size_t)gridDim.x*blockDim.x){
    size_t flat = i*4;
    int c = (int)(flat & (NC-1));
    int b = (int)(flat >> 21);
    int g = c >> 4;
    float s1 = stats[(b*NG+g)*2], s2 = stats[(b*NG+g)*2+1];
    float mean = s1*inv_cnt;
    float rstd = rsqrtf(s2*inv_cnt - mean*mean + 1e-6f);
    float4 v = *(const float4*)(x + flat);
    float4 sc = *(const float4*)(gsc + c);
    float4 bi = *(const float4*)(gbi + c);
    ushort4 o;
    o.x = f2bf((v.x-mean)*rstd*sc.x + bi.x);
    o.y = f2bf((v.y-mean)*rstd*sc.y + bi.y);
    o.z = f2bf((v.z-mean)*rstd*sc.z + bi.z);
    o.w = f2bf((v.w-mean)*rstd*sc.w + bi.w);
    *(ushort4*)(hn + flat) = o;
  }
}

__global__ __launch_bounds__(256) void k_wtrans4(const float* __restrict__ wq, const float* __restrict__ wk,
    const float* __restrict__ wv, const float* __restrict__ wo,
    u16* __restrict__ wqkvT, u16* __restrict__ woT){
  int j = blockIdx.x*256 + threadIdx.x;
  int wsel = j >> 18, r = j & 262143;
  int n = r >> 9, k = r & 511;
  const float* src = wsel==0?wq : wsel==1?wk : wsel==2?wv : wo;
  u16 v = f2bf(src[k*512 + n]);
  if (wsel < 3) wqkvT[(size_t)wsel*262144 + r] = v;
  else          woT[r] = v;
}

__global__ __launch_bounds__(256) void k_sumred(const float* __restrict__ part, float* __restrict__ sums){
  int row = blockIdx.x*4 + (threadIdx.x >> 6);
  int l = threadIdx.x & 63;
  float s = part[(size_t)row*64 + l];
  #pragma unroll
  for (int o = 32; o; o >>= 1) s += __shfl_xor(s, o);
  if (l == 0) sums[row] = s;
}

__global__ __launch_bounds__(256) void k_pvred(const u16* __restrict__ op, const float* __restrict__ sums,
    u16* __restrict__ o){
  size_t i = ((size_t)blockIdx.x*256 + threadIdx.x)*8;
  int row = (int)(i >> 9);
  float inv = 1.f/sums[row];
  uint4 a = *(const uint4*)(op + i);
  uint4 b = *(const uint4*)(op + (size_t)NM*NC + i);
  uint32_t pa[4] = {a.x,a.y,a.z,a.w}, pb[4] = {b.x,b.y,b.z,b.w};
  uint32_t r[4];
  #pragma unroll
  for (int j=0;j<4;j++){
    float lo = (bfu(pa[j] & 0xFFFFu) + bfu(pb[j] & 0xFFFFu)) * inv;
    float hi = (__builtin_bit_cast(float, pa[j] & 0xFFFF0000u) +
                __builtin_bit_cast(float, pb[j] & 0xFFFF0000u)) * inv;
    r[j] = (uint32_t)f2bf(lo) | ((uint32_t)f2bf(hi) << 16);
  }
  *(uint4*)(o + i) = make_uint4(r[0], r[1], r[2], r[3]);
}

// ---------------- 256x256 8-phase GEMM (T1+T2+T3+T4+T5) ----------------
// B-column remap: ldB reads B-row (4*frow + n) so each lane's 4 n-values are
// 4 CONSECUTIVE output columns -> packed 8B/16B coalesced epilogue stores.
#define PH_A  { __builtin_amdgcn_sched_barrier(0); __builtin_amdgcn_s_barrier(); \
  asm volatile("s_waitcnt lgkmcnt(0)" ::: "memory"); __builtin_amdgcn_sched_barrier(0); \
  __builtin_amdgcn_s_setprio(1); }
#define PH_B  { __builtin_amdgcn_s_setprio(0); __builtin_amdgcn_sched_barrier(0); \
  __builtin_amdgcn_s_barrier(); }
#define PH_BV { __builtin_amdgcn_s_setprio(0); __builtin_amdgcn_sched_barrier(0); \
  asm volatile("s_waitcnt vmcnt(8)" ::: "memory"); __builtin_amdgcn_s_barrier(); }

template<int MODE>
__global__ __launch_bounds__(512, 2) void k_gemm8(
    const u16* __restrict__ A, const u16* __restrict__ B,
    size_t aBatch, size_t bBatch, int lda_, int ldb_, int Klen, float alpha,
    void* __restrict__ out0, void* __restrict__ out1, void* __restrict__ out2,
    const float* __restrict__ bias0, const float* __restrict__ bias1, const float* __restrict__ bias2,
    const float* __restrict__ aux1)
{
  __shared__ u16 LDS[65536];   // 128 KiB
  const size_t lda = lda_, ldb = ldb_;
  const int t = threadIdx.x;
  const int l = t & 63, w = t >> 6;
  const int wr = w >> 2, wc = w & 3;
  const int frow = l & 15, kq = l >> 4;
  // XCD-aware bijective remap
  const int nx = gridDim.x, ny = gridDim.y;
  int f = ((int)blockIdx.z*ny + (int)blockIdx.y)*nx + (int)blockIdx.x;
  const int nwg = nx*ny*(int)gridDim.z;
  f = (f & 7)*(nwg >> 3) + (f >> 3);
  const int bx = f % nx; const int t2 = f / nx;
  const int by = t2 % ny; const int bz = t2 / ny;
  int bb = 0, kOff = 0;
  if constexpr (MODE == 1) bb = bz;
  if constexpr (MODE == 4){ bb = bz & 3; kOff = (bz >> 2)*(NSEQ/2); }
  const int brow = by*256, bcol = bx*256;

  f32x4 acc[8][4] = {};
  // staging: thread t covers row (t>>3); 16B slot (t&7) pre-swizzled to match SWZ
  const int kswz = 8*(((t&7) ^ (t>>3) ^ (t>>5)) & 7);
  const u16* Ast = A + (size_t)bb*aBatch + (size_t)(brow + (t>>3))*lda + kOff + kswz;
  const u16* Bst = B + (size_t)bb*bBatch + (size_t)(bcol + (t>>3))*ldb + kOff + kswz;
  char* Lb = (char*)LDS;
  char* stD = Lb + t*16;

  auto stage = [&](int buf, int isB, int half, int kt){
    const u16* s = (isB ? Bst : Ast) + (size_t)(half*128)*(isB?ldb:lda) + (size_t)kt*64;
    char* d = stD + buf*65536 + isB*32768 + half*16384;
    gll16(s, d);
    gll16(s + (size_t)64*(isB?ldb:lda), d + 8192);
  };
  auto ldA = [&](int buf, int quad, bf16x8* dst){
    const char* base = Lb + buf*65536 + wr*16384;
    #pragma unroll
    for (int mf=0; mf<4; mf++)
      #pragma unroll
      for (int ks=0; ks<2; ks++){
        int rl = quad*64 + mf*16 + frow;
        int byte = (rl*128 + ks*64 + kq*16) ^ SWZ(rl);
        dst[mf*2+ks] = *(const bf16x8*)(base + byte);
      }
  };
  auto ldB = [&](int buf, int qc, bf16x8* dst){
    const char* base = Lb + buf*65536 + 32768 + (wc>>1)*16384;
    #pragma unroll
    for (int nf=0; nf<2; nf++)
      #pragma unroll
      for (int ks=0; ks<2; ks++){
        int rl = (wc&1)*64 + 4*frow + qc*2 + nf;   // col remap: lane's n-values adjacent
        int byte = (rl*128 + ks*64 + kq*16) ^ SWZ(rl);
        dst[nf*2+ks] = *(const bf16x8*)(base + byte);
      }
  };
  auto quad = [&](int qr, int qc, const bf16x8* af, const bf16x8* bf){
    #pragma unroll
    for (int mf=0; mf<4; mf++)
      #pragma unroll
      for (int nf=0; nf<2; nf++)
        #pragma unroll
        for (int ks=0; ks<2; ks++)
          acc[qr*4+mf][qc*2+nf] = MFMA_(af[mf*2+ks], bf[nf*2+ks], acc[qr*4+mf][qc*2+nf]);
  };

  bf16x8 af[8], b0[4], b1[4];
  const int NT = Klen >> 6;
  stage(0,0,0,0); stage(0,0,1,0); stage(0,1,0,0); stage(0,1,1,0);
  stage(1,0,0,1); stage(1,0,1,1); stage(1,1,0,1); stage(1,1,1,1);
  asm volatile("s_waitcnt vmcnt(8)" ::: "memory");
  __builtin_amdgcn_s_barrier();

  for (int i = 0; i < (NT>>1); i++){
    const int st0 = (2*i+2 < NT) ? 2*i+2 : NT-1;
    const int st1 = (2*i+3 < NT) ? 2*i+3 : NT-1;
    ldA(0,0,af); ldB(0,0,b0);
    PH_A; quad(0,0,af,b0); PH_B;
    ldB(0,1,b1);
    PH_A; quad(0,1,af,b1); PH_B;
    ldA(0,1,af);
    stage(0,1,0,st0); stage(0,1,1,st0);
    PH_A; quad(1,0,af,b0); PH_B;
    stage(0,0,0,st0); stage(0,0,1,st0);
    PH_A; quad(1,1,af,b1); PH_BV;
    ldA(1,0,af); ldB(1,0,b0);
    PH_A; quad(0,0,af,b0); PH_B;
    ldB(1,1,b1);
    PH_A; quad(0,1,af,b1); PH_B;
    ldA(1,1,af);
    stage(1,1,0,st1); stage(1,1,1,st1);
    PH_A; quad(1,0,af,b0); PH_B;
    stage(1,0,0,st1); stage(1,0,1,st1);
    PH_A; quad(1,1,af,b1); PH_BV;
  }

  // ---------------- epilogue (packed coalesced stores) ----------------
  const int col4 = wc*64 + 4*frow;            // lane's 4 consecutive cols (local)
  if constexpr (MODE==0){
    const int seg = bcol >> 9;
    const int colr = (bcol & 511) + col4;
    if (seg < 2){
      u16* dq = (u16*)(seg==0 ? out0 : out1);
      const float* bp = seg==0 ? bias0 : bias1;
      const float4 bi = *(const float4*)(bp + colr);
      #pragma unroll
      for (int m=0;m<8;m++){
        #pragma unroll
        for (int r=0;r<4;r++){
          const int rr = brow + wr*128 + m*16 + kq*4 + r;
          uint2 wv;
          wv.x = pk2(acc[m][0][r]+bi.x, acc[m][1][r]+bi.y);
          wv.y = pk2(acc[m][2][r]+bi.z, acc[m][3][r]+bi.w);
          *(uint2*)&dq[(size_t)rr*NC + colr] = wv;
        }
      }
    } else {
      const float4 bi = *(const float4*)(bias2 + colr);
      const float bvs[4] = {bi.x, bi.y, bi.z, bi.w};
      #pragma unroll
      for (int m=0;m<8;m++){
        const int rr0 = brow + wr*128 + m*16 + kq*4;
        const int b = rr0 >> 12, sq = rr0 & 4095;
        #pragma unroll
        for (int n=0;n<4;n++){
          uint2 wv;
          wv.x = pk2(acc[m][n][0]+bvs[n], acc[m][n][1]+bvs[n]);
          wv.y = pk2(acc[m][n][2]+bvs[n], acc[m][n][3]+bvs[n]);
          *(uint2*)&((u16*)out2)[((size_t)(b*NC + colr + n) << 12) + sq] = wv;
        }
      }
    }
  } else if constexpr (MODE==1){
    u16* Pp = (u16*)out0 + (size_t)bb*NSEQ*NSEQ;
    #pragma unroll
    for (int m=0;m<8;m++){
      #pragma unroll
      for (int r=0;r<4;r++){
        const int rr = brow + wr*128 + m*16 + kq*4 + r;
        float e0 = __expf(alpha*acc[m][0][r]);
        float e1 = __expf(alpha*acc[m][1][r]);
        float e2 = __expf(alpha*acc[m][2][r]);
        float e3 = __expf(alpha*acc[m][3][r]);
        uint2 wv; wv.x = pk2(e0, e1); wv.y = pk2(e2, e3);
        *(uint2*)&Pp[(size_t)rr*NSEQ + bcol + col4] = wv;
        float rs = bfu(wv.x & 0xFFFFu) + bfu(wv.x >> 16) + bfu(wv.y & 0xFFFFu) + bfu(wv.y >> 16);
        rs += __shfl_xor(rs, 1); rs += __shfl_xor(rs, 2);
        rs += __shfl_xor(rs, 4); rs += __shfl_xor(rs, 8);
        if (frow == 0)
          ((float*)out1)[((size_t)bb*NSEQ + rr)*64 + bx*4 + wc] = rs;
      }
    }
  } else if constexpr (MODE==4){
    const int sp = bz >> 2;
    u16* op = (u16*)out0 + (size_t)sp*NM*NC + (size_t)bb*NSEQ*NC;
    #pragma unroll
    for (int m=0;m<8;m++){
      #pragma unroll
      for (int r=0;r<4;r++){
        const int rr = brow + wr*128 + m*16 + kq*4 + r;
        uint2 wv;
        wv.x = pk2(acc[m][0][r], acc[m][1][r]);
        wv.y = pk2(acc[m][2][r], acc[m][3][r]);
        *(uint2*)&op[(size_t)rr*NC + bcol + col4] = wv;
      }
    }
  } else {
    const int c = bcol + col4;
    const float4 bi = *(const float4*)(bias0 + c);
    #pragma unroll
    for (int m=0;m<8;m++){
      #pragma unroll
      for (int r=0;r<4;r++){
        const int rr = brow + wr*128 + m*16 + kq*4 + r;
        const float4 res = *(const float4*)(aux1 + (size_t)rr*NC + c);
        float4 ov;
        ov.x = acc[m][0][r] + bi.x + res.x;
        ov.y = acc[m][1][r] + bi.y + res.y;
        ov.z = acc[m][2][r] + bi.z + res.z;
        ov.w = acc[m][3][r] + bi.w + res.w;
        *(float4*)&((float*)out0)[(size_t)rr*NC + c] = ov;
      }
    }
  }
}

extern "C" void kernel_launch(void* const* d_in, const int* in_sizes, int n_in,
                              void* d_out, int out_size, void* d_ws, size_t ws_size,
                              hipStream_t stream){
  const float* x   = (const float*)d_in[0];
  const float* gsc = (const float*)d_in[1];
  const float* gbi = (const float*)d_in[2];
  const float* wq  = (const float*)d_in[3];
  const float* bq  = (const float*)d_in[4];
  const float* wk  = (const float*)d_in[5];
  const float* bk  = (const float*)d_in[6];
  const float* wv  = (const float*)d_in[7];
  const float* bv  = (const float*)d_in[8];
  const float* wo  = (const float*)d_in[9];
  const float* bo  = (const float*)d_in[10];
  float* out = (float*)d_out;

  char* wsp = (char*)d_ws;
  size_t off = 0;
  auto alloc = [&](size_t bytes)->void*{ void* p = wsp + off; off += (bytes + 255) & ~(size_t)255; return p; };
  float* stats   = (float*)alloc((size_t)NB*NG*2*sizeof(float));
  float* sums    = (float*)alloc((size_t)NM*sizeof(float));
  float* partsum = (float*)alloc((size_t)NM*64*sizeof(float));
  u16* hn    = (u16*)alloc((size_t)NM*NC*2);
  u16* wqkvT = (u16*)alloc((size_t)3*NC*NC*2);
  u16* woT   = (u16*)alloc((size_t)NC*NC*2);
  u16* q     = (u16*)alloc((size_t)NM*NC*2);
  u16* kk    = (u16*)alloc((size_t)NM*NC*2);
  u16* vT    = (u16*)alloc((size_t)NM*NC*2);
  u16* o     = (u16*)alloc((size_t)NM*NC*2);
  u16* P     = (u16*)alloc((size_t)NB*NSEQ*NSEQ*2);
  u16* opart = q;  // PV split-K partials [2][NM][NC] alias dead q+kk (32 MiB)

  k_zero<<<1,256,0,stream>>>(stats, NB*NG*2);
  k_gn_stats<<<NB*NG*8,256,0,stream>>>(x, stats);
  k_gn_apply<<<2048,256,0,stream>>>(x, stats, gsc, gbi, hn);
  k_wtrans4<<<4096,256,0,stream>>>(wq, wk, wv, wo, wqkvT, woT);

  // QKV projection: M=16384, N=1536, K=512
  k_gemm8<0><<<dim3(6,64,1),512,0,stream>>>(hn, wqkvT, 0, 0, NC, NC, NC, 1.f,
      q, kk, vT, bq, bk, bv, nullptr);

  const float scale = 0.044194173824159216f;  // 512^-0.5
  // QK^T all batches + exp + row partials: M=N=4096, K=512, z=4
  k_gemm8<1><<<dim3(16,16,NB),512,0,stream>>>(q, kk,
      (size_t)NSEQ*NC, (size_t)NSEQ*NC, NC, NC, NC, scale,
      P, partsum, nullptr, nullptr, nullptr, nullptr, nullptr);
  k_sumred<<<NM/4,256,0,stream>>>(partsum, sums);
  // PV split-K=2: M=4096, N=512, Klen=2048, z=(split,b) -> 256 blocks
  k_gemm8<4><<<dim3(2,16,8),512,0,stream>>>(P, vT,
      (size_t)NSEQ*NSEQ, (size_t)NC*NSEQ, NSEQ, NSEQ, NSEQ/2, 1.f,
      opart, nullptr, nullptr, nullptr, nullptr, nullptr, nullptr);
  k_pvred<<<NM*NC/8/256,256,0,stream>>>(opart, sums, o);
  // output projection + bias + residual: M=16384, N=512, K=512
  k_gemm8<3><<<dim3(2,64,1),512,0,stream>>>(o, woT, 0, 0, NC, NC, NC, 1.f,
      out, nullptr, nullptr, bo, nullptr, nullptr, x);
}